// Round 3
// baseline (40.402 us; speedup 1.0000x reference)
//
#include <hip/hip_runtime.h>

#define NR_ACTIONS 64
#define VEC 512
#define NTILE 64        // output columns per block (16 per wave)
#define MAXB 2048       // max batch the in-LDS list supports

typedef short bf16x8 __attribute__((ext_vector_type(8)));
typedef float f32x4  __attribute__((ext_vector_type(4)));

__device__ __forceinline__ ushort f2bf(float f) {
    union { float f; uint32_t u; } x; x.f = f;
    uint32_t r = x.u + 0x7FFFu + ((x.u >> 16) & 1u);   // round-to-nearest-even
    return (ushort)(r >> 16);
}

// ---------------- Single fused kernel: list build + direct-stream MFMA ----------------
// Block = 256 threads (4 waves). blockIdx = (col-tile, action).
// Wave w owns cols [j0 + 16w, +16). No barriers in the hot loop: B-fragments are
// loaded straight from W (8 scalar dwords/lane; every 64B line fully consumed by a
// quarter-wave), A-fragments straight from v (2 dwordx4/lane), both cvt'd to bf16
// in-register. k-map for A and B is identical (k = ks*32 + (lane>>4)*8 + e), so the
// contraction is exact regardless of the HW's internal k-order.
__global__ __launch_bounds__(256) void grouped_direct(
    const float* __restrict__ v, const int* __restrict__ action,
    const float* __restrict__ W, float* __restrict__ out, int batch)
{
    __shared__ int list[MAXB];
    __shared__ int mcount;

    const int a    = blockIdx.y;
    const int j0   = blockIdx.x * NTILE;
    const int tid  = threadIdx.x;
    const int lane = tid & 63;
    const int w    = tid >> 6;

    if (tid == 0) mcount = 0;
    __syncthreads();
    // ballot-compaction of rows with action[i]==a (order within group irrelevant:
    // each row's dot product is computed independently -> deterministic output)
    for (int i0 = tid; i0 < batch; i0 += 256) {
        const bool hit = (action[i0] == a);
        const unsigned long long mask = __ballot(hit);
        int base = 0;
        if (lane == 0) base = atomicAdd(&mcount, __popcll(mask));
        base = __shfl(base, 0);
        if (hit)
            list[base + __popcll(mask & ((1ull << lane) - 1ull))] = i0;
    }
    __syncthreads();
    const int m = mcount;
    if (m == 0) return;

    const float* Wa   = W + (size_t)a * VEC * VEC;
    const int    colg = j0 + w * 16 + (lane & 15);
    const int    g    = lane >> 4;            // k-group of this lane

    for (int mbase = 0; mbase < m; mbase += 64) {
        const int nrb = min(4, (m - mbase + 15) >> 4);   // active 16-row blocks

        // hoist per-lane A row pointers (row = lane&15 within each 16-row block)
        const float* vp[4];
#pragma unroll
        for (int r = 0; r < 4; ++r) {
            const int row_l = mbase + r * 16 + (lane & 15);
            const int idx   = (row_l < m) ? list[row_l] : list[mbase];  // clamp: pad rows discarded at store
            vp[r] = v + (size_t)idx * VEC + g * 8;
        }

        f32x4 acc[4];
#pragma unroll
        for (int r = 0; r < 4; ++r) acc[r] = (f32x4){0.f, 0.f, 0.f, 0.f};

#pragma unroll 4
        for (int ks = 0; ks < VEC / 32; ++ks) {
            // ---- B fragment: 8 strided scalar loads from W, cvt to bf16 ----
            const float* wp = Wa + (size_t)(ks * 32 + g * 8) * VEC + colg;
            float wv[8];
#pragma unroll
            for (int e = 0; e < 8; ++e) wv[e] = wp[(size_t)e * VEC];
            bf16x8 bfrag;
#pragma unroll
            for (int e = 0; e < 8; ++e) bfrag[e] = (short)f2bf(wv[e]);

            // ---- A fragments + MFMA ----
#pragma unroll
            for (int r = 0; r < 4; ++r) {
                if (r < nrb) {
                    const float* ap = vp[r] + ks * 32;
                    float av[8];
                    *(float4*)&av[0] = *(const float4*)(ap);
                    *(float4*)&av[4] = *(const float4*)(ap + 4);
                    bf16x8 afrag;
#pragma unroll
                    for (int e = 0; e < 8; ++e) afrag[e] = (short)f2bf(av[e]);
                    acc[r] = __builtin_amdgcn_mfma_f32_16x16x32_bf16(
                        afrag, bfrag, acc[r], 0, 0, 0);
                }
            }
        }

        // ---- store: D layout col=lane&15, row=(lane>>4)*4+q (m89-verified) ----
#pragma unroll
        for (int r = 0; r < 4; ++r) {
            if (r < nrb) {
#pragma unroll
                for (int q = 0; q < 4; ++q) {
                    const int row_l = mbase + r * 16 + (lane >> 4) * 4 + q;
                    if (row_l < m)
                        out[(size_t)list[row_l] * VEC + colg] = acc[r][q];
                }
            }
        }
    }
}

// ---------------- Fallback: naive per-row (only if batch > MAXB) ----------------
__global__ void naive_vm(const float* __restrict__ v, const float* __restrict__ W,
                         const int* __restrict__ action, float* __restrict__ out) {
    const int b = blockIdx.x;
    const int a = action[b];
    const float* wbase = W + (size_t)a * VEC * VEC;
    const float* vb = v + (size_t)b * VEC;
    const int j = threadIdx.x;
    float acc0 = 0.f, acc1 = 0.f;
    for (int k = 0; k < VEC; ++k) {
        const float vk = vb[k];
        acc0 = fmaf(vk, wbase[(size_t)k * VEC + j], acc0);
        acc1 = fmaf(vk, wbase[(size_t)k * VEC + j + 256], acc1);
    }
    out[(size_t)b * VEC + j] = acc0;
    out[(size_t)b * VEC + j + 256] = acc1;
}

extern "C" void kernel_launch(void* const* d_in, const int* in_sizes, int n_in,
                              void* d_out, int out_size, void* d_ws, size_t ws_size,
                              hipStream_t stream) {
    const float* v      = (const float*)d_in[0];
    const int*   action = (const int*)d_in[1];
    const float* W      = (const float*)d_in[2];
    float* out = (float*)d_out;
    const int batch = in_sizes[1];

    if (batch > MAXB) {
        naive_vm<<<batch, 256, 0, stream>>>(v, W, action, out);
        return;
    }
    grouped_direct<<<dim3(VEC / NTILE, NR_ACTIONS), 256, 0, stream>>>(
        v, action, W, out, batch);
}

// Round 4
// 38.086 us; speedup vs baseline: 1.0608x; 1.0608x over previous
//
#include <hip/hip_runtime.h>

#define NR_ACTIONS 64
#define VEC 512
#define NTILE 16            // output columns per block (one 16-col MFMA tile)
#define KPITCH (VEC + 8)    // 520 bf16: 16B-aligned cols, 2-way-max banks (free)

typedef short bf16x8 __attribute__((ext_vector_type(8)));
typedef float f32x4  __attribute__((ext_vector_type(4)));

__device__ __forceinline__ ushort f2bf(float f) {
    union { float f; uint32_t u; } x; x.f = f;
    uint32_t r = x.u + 0x7FFFu + ((x.u >> 16) & 1u);   // RNE
    return (ushort)(r >> 16);
}
__device__ __forceinline__ uint32_t pack2(float a, float b) {
    return (uint32_t)f2bf(a) | ((uint32_t)f2bf(b) << 16);
}

// ---- prep: v fp32 -> bf16 once (kills per-fragment cvt in the hot kernel) ----
__global__ __launch_bounds__(256) void cvt_v_kernel(const float* __restrict__ v,
                                                    ushort* __restrict__ vbf, int n8) {
    const int i = blockIdx.x * 256 + threadIdx.x;
    if (i < n8) {
        const float4 x = ((const float4*)v)[2 * i];
        const float4 y = ((const float4*)v)[2 * i + 1];
        uint4 o;
        o.x = pack2(x.x, x.y); o.y = pack2(x.z, x.w);
        o.z = pack2(y.x, y.y); o.w = pack2(y.z, y.w);
        ((uint4*)vbf)[i] = o;
    }
}

// ---- main: one block = one (action, 16-col) W-tile streamer + MFMA ----
// 4 waves. Stage full 512x16 W tile (8 dwordx4/thread in flight), cvt->bf16,
// col-major LDS, ONE barrier, then each wave computes 16 rows of the group.
// Row list built by wave0 via ORDERED ballot scan (deterministic windows).
template <bool BF>
__global__ __launch_bounds__(256) void grouped(
    const float* __restrict__ v, const ushort* __restrict__ vbf,
    const int* __restrict__ action, const float* __restrict__ W,
    float* __restrict__ out, int batch)
{
    __shared__ ushort sB[NTILE * KPITCH];   // 16.25 KB
    __shared__ ushort slist[64];
    __shared__ int smc;

    const int h  = blockIdx.x;
    const int l  = (h & 7) * ((int)gridDim.x >> 3) + (h >> 3);  // XCD-bijective (nwg%8==0)
    const int a  = l >> 5;                 // action
    const int j0 = (l & 31) * NTILE;       // column tile
    const int tid  = threadIdx.x;
    const int lane = tid & 63;
    const int wv   = tid >> 6;

    const float* Wa = W + (size_t)a * VEC * VEC;

    // ---- issue W-tile loads: 8 dwordx4/thread, back-to-back (8 KB/wave in flight) ----
    float4 wreg[8];
    const int c4 = (tid & 3) * 4;          // 4 cols of 16
    const int kq = (tid >> 2) * 4;         // k-quad base, 0..252
#pragma unroll
    for (int p = 0; p < 2; ++p)
#pragma unroll
        for (int i = 0; i < 4; ++i)
            wreg[p * 4 + i] = *(const float4*)(Wa + (size_t)(p * 256 + kq + i) * VEC + j0 + c4);

    // ---- wave0: ordered scan for window 0 (overlaps other waves' cvt/write) ----
    if (wv == 0) {
        int base = 0;
        for (int it = 0; it < batch; it += 64) {
            const int idx = it + lane;
            const bool hit = (idx < batch) && (action[idx] == a);
            const unsigned long long mk = __ballot(hit);
            const int pos = base + __popcll(mk & ((1ull << lane) - 1ull));
            if (hit && pos < 64) slist[pos] = (ushort)idx;
            base += __popcll(mk);
        }
        if (lane == 0) smc = base;
    }

    // ---- cvt + transposed write: sB[col][k] bf16, 4k packed per uint2 ----
#pragma unroll
    for (int p = 0; p < 2; ++p)
#pragma unroll
        for (int c = 0; c < 4; ++c) {
            uint2 w2;
            w2.x = pack2((&wreg[p * 4 + 0].x)[c], (&wreg[p * 4 + 1].x)[c]);
            w2.y = pack2((&wreg[p * 4 + 2].x)[c], (&wreg[p * 4 + 3].x)[c]);
            *(uint2*)&sB[(c4 + c) * KPITCH + p * 256 + kq] = w2;
        }
    __syncthreads();   // the only barrier in the common path

    const int m     = smc;
    const int colg  = j0 + (lane & 15);
    const int g     = lane >> 4;
    const int wstart = wv * 16;            // wave's 16-row sub-block within window

    for (int wlo = 0;;) {
        const int mw = min(64, m - wlo);
        if (mw > 0 && wstart < mw) {
            const int rl   = wstart + (lane & 15);
            const int ridx = slist[rl < mw ? rl : wstart];   // clamp: discarded at store
            f32x4 acc = {0.f, 0.f, 0.f, 0.f};
            if (BF) {
                const ushort* ap = vbf + (size_t)ridx * VEC;
#pragma unroll
                for (int ks = 0; ks < 16; ++ks) {
                    const bf16x8 bfrag = *(const bf16x8*)&sB[(lane & 15) * KPITCH + ks * 32 + g * 8];
                    const bf16x8 afrag = *(const bf16x8*)(ap + ks * 32 + g * 8);
                    acc = __builtin_amdgcn_mfma_f32_16x16x32_bf16(afrag, bfrag, acc, 0, 0, 0);
                }
            } else {
                const float* ap = v + (size_t)ridx * VEC;
#pragma unroll
                for (int ks = 0; ks < 16; ++ks) {
                    const bf16x8 bfrag = *(const bf16x8*)&sB[(lane & 15) * KPITCH + ks * 32 + g * 8];
                    float av[8];
                    *(float4*)&av[0] = *(const float4*)(ap + ks * 32 + g * 8);
                    *(float4*)&av[4] = *(const float4*)(ap + ks * 32 + g * 8 + 4);
                    bf16x8 afrag;
#pragma unroll
                    for (int e = 0; e < 8; ++e) afrag[e] = (short)f2bf(av[e]);
                    acc = __builtin_amdgcn_mfma_f32_16x16x32_bf16(afrag, bfrag, acc, 0, 0, 0);
                }
            }
            // D layout: col=lane&15, row=(lane>>4)*4+q (m89-verified)
#pragma unroll
            for (int q = 0; q < 4; ++q) {
                const int row = wstart + g * 4 + q;
                if (row < mw)
                    out[(size_t)slist[row] * VEC + colg] = acc[q];
            }
        }
        wlo += 64;
        if (wlo >= m) break;               // uniform; common case exits here, 1 barrier total
        // rare path (group > 64 rows): rebuild ordered window list
        __syncthreads();
        if (wv == 0) {
            int base = 0;
            for (int it = 0; it < batch; it += 64) {
                const int idx = it + lane;
                const bool hit = (idx < batch) && (action[idx] == a);
                const unsigned long long mk = __ballot(hit);
                const int pos = base + __popcll(mk & ((1ull << lane) - 1ull));
                const int rp  = pos - wlo;
                if (hit && rp >= 0 && rp < 64) slist[rp] = (ushort)idx;
                base += __popcll(mk);
            }
        }
        __syncthreads();
    }
}

extern "C" void kernel_launch(void* const* d_in, const int* in_sizes, int n_in,
                              void* d_out, int out_size, void* d_ws, size_t ws_size,
                              hipStream_t stream) {
    const float* v      = (const float*)d_in[0];
    const int*   action = (const int*)d_in[1];
    const float* W      = (const float*)d_in[2];
    float* out = (float*)d_out;
    const int batch = in_sizes[1];
    if (batch <= 0) return;

    const int nblocks = (VEC / NTILE) * NR_ACTIONS;   // 2048 (%8==0 for swizzle)
    const size_t need = (size_t)batch * VEC * sizeof(ushort);

    if (ws_size >= need && ((size_t)batch * VEC) % 8 == 0) {
        ushort* vbf = (ushort*)d_ws;
        const int n8 = batch * VEC / 8;
        cvt_v_kernel<<<(n8 + 255) / 256, 256, 0, stream>>>(v, vbf, n8);
        grouped<true><<<nblocks, 256, 0, stream>>>(v, vbf, action, W, out, batch);
    } else {
        grouped<false><<<nblocks, 256, 0, stream>>>(v, (const ushort*)nullptr, action, W, out, batch);
    }
}

// Round 5
// 30.385 us; speedup vs baseline: 1.3297x; 1.2535x over previous
//
#include <hip/hip_runtime.h>

#define NR_ACTIONS 64
#define VEC 512
#define NTILE 16        // output columns per block (one 16-col MFMA tile)
#define MAXB 2048       // fast-scan path size

typedef short bf16x8 __attribute__((ext_vector_type(8)));
typedef float f32x4  __attribute__((ext_vector_type(4)));

__device__ __forceinline__ ushort f2bf(float f) {
    union { float f; uint32_t u; } x; x.f = f;
    uint32_t r = x.u + 0x7FFFu + ((x.u >> 16) & 1u);   // RNE
    return (ushort)(r >> 16);
}
__device__ __forceinline__ uint32_t pack2(float a, float b) {
    return (uint32_t)f2bf(a) | ((uint32_t)f2bf(b) << 16);
}

// ---- prep: v fp32 -> bf16 once ----
__global__ __launch_bounds__(256) void cvt_v_kernel(const float* __restrict__ v,
                                                    ushort* __restrict__ vbf, int n8) {
    const int i = blockIdx.x * 256 + threadIdx.x;
    if (i < n8) {
        const float4 x = ((const float4*)v)[2 * i];
        const float4 y = ((const float4*)v)[2 * i + 1];
        uint4 o;
        o.x = pack2(x.x, x.y); o.y = pack2(x.z, x.w);
        o.z = pack2(y.x, y.y); o.w = pack2(y.z, y.w);
        ((uint4*)vbf)[i] = o;
    }
}

// ---- main: one block = one (action, 16-col) tile ----
// Staging: global_load_lds (fire-and-forget, no reg deps) of the 512x16 fp32
// W tile, k-major linear LDS. Scan: batched reg loads + reg-only ballot chain.
// ONE barrier, then MFMA with cvt-at-fragment-assembly.
template <bool BF>
__global__ __launch_bounds__(256) void grouped(
    const float* __restrict__ v, const ushort* __restrict__ vbf,
    const int* __restrict__ action, const float* __restrict__ W,
    float* __restrict__ out, int batch)
{
    __shared__ float  sW[NTILE * VEC];   // 32 KB, sW[k*16 + col]
    __shared__ ushort slist[64];
    __shared__ int    smc;

    const int h    = blockIdx.x;
    const int l    = (h & 7) * ((int)gridDim.x >> 3) + (h >> 3);  // XCD-bijective (nwg%8==0)
    const int a    = l >> 5;
    const int j0   = (l & 31) * NTILE;
    const int tid  = threadIdx.x;
    const int lane = tid & 63;
    const int wv   = tid >> 6;

    const float* Wa = W + (size_t)a * VEC * VEC + j0;

    // wave0: issue the 32 independent action loads FIRST (vmcnt is in-order
    // per wave -> scan data must not queue behind this wave's W staging).
    const bool fast = (batch == MAXB);
    int av[32];
    if (wv == 0 && fast) {
#pragma unroll
        for (int c = 0; c < 32; ++c) av[c] = action[c * 64 + lane];
    }

    // all waves: fire-and-forget W tile -> LDS. Lane i of call c covers LDS
    // dwords (wv*8+c)*256 + 4i .. +3  ==  k = (wv*8+c)*16 + (i>>2), col = 4*(i&3)..+3.
    {
        const int col4 = (lane & 3) * 4;
        const int krow = lane >> 2;
#pragma unroll
        for (int c = 0; c < 8; ++c) {
            const int kr = (wv * 8 + c) * 16 + krow;
            const float* gp = Wa + (size_t)kr * VEC + col4;
            __builtin_amdgcn_global_load_lds(
                (const __attribute__((address_space(1))) void*)gp,
                (__attribute__((address_space(3))) void*)&sW[(wv * 8 + c) * 256],
                16, 0, 0);
        }
    }

    // wave0: ordered window-0 list (register-only ballot chain on fast path)
    if (wv == 0) {
        int base = 0;
        if (fast) {
#pragma unroll
            for (int c = 0; c < 32; ++c) {
                const bool hit = (av[c] == a);
                const unsigned long long mk = __ballot(hit);
                const int pos = base + __popcll(mk & ((1ull << lane) - 1ull));
                if (hit && pos < 64) slist[pos] = (ushort)(c * 64 + lane);
                base += __popcll(mk);
            }
        } else {
            for (int it = 0; it < batch; it += 64) {
                const int idx = it + lane;
                const bool hit = (idx < batch) && (action[idx] == a);
                const unsigned long long mk = __ballot(hit);
                const int pos = base + __popcll(mk & ((1ull << lane) - 1ull));
                if (hit && pos < 64) slist[pos] = (ushort)idx;
                base += __popcll(mk);
            }
        }
        if (lane == 0) smc = base;
    }

    __syncthreads();   // drains vmcnt (W tile landed) + publishes slist/smc

    const int m      = smc;
    const int colg   = j0 + (lane & 15);
    const int g      = lane >> 4;
    const int wstart = wv * 16;

    for (int wlo = 0;;) {
        const int mw = min(64, m - wlo);
        if (mw > 0 && wstart < mw) {
            const int rl   = wstart + (lane & 15);
            const int ridx = slist[rl < mw ? rl : wstart];   // clamp: discarded at store
            f32x4 acc = {0.f, 0.f, 0.f, 0.f};
#pragma unroll
            for (int ks = 0; ks < 16; ++ks) {
                bf16x8 bfrag;
#pragma unroll
                for (int e = 0; e < 8; ++e) {
                    const int kk = ks * 32 + g * 8 + e;
                    bfrag[e] = (short)f2bf(sW[kk * 16 + (lane & 15)]);
                }
                bf16x8 afrag;
                if (BF) {
                    afrag = *(const bf16x8*)(vbf + (size_t)ridx * VEC + ks * 32 + g * 8);
                } else {
                    const float* ap = v + (size_t)ridx * VEC + ks * 32 + g * 8;
                    float avv[8];
                    *(float4*)&avv[0] = *(const float4*)(ap);
                    *(float4*)&avv[4] = *(const float4*)(ap + 4);
#pragma unroll
                    for (int e = 0; e < 8; ++e) afrag[e] = (short)f2bf(avv[e]);
                }
                acc = __builtin_amdgcn_mfma_f32_16x16x32_bf16(afrag, bfrag, acc, 0, 0, 0);
            }
            // D layout: col=lane&15, row=(lane>>4)*4+q (m89-verified)
#pragma unroll
            for (int q = 0; q < 4; ++q) {
                const int row = wstart + g * 4 + q;
                if (row < mw)
                    out[(size_t)slist[row] * VEC + colg] = acc[q];
            }
        }
        wlo += 64;
        if (wlo >= m) break;   // uniform; common case: 1 barrier total
        // rare path (group > 64 rows): rebuild ordered window list
        __syncthreads();
        if (wv == 0) {
            int base = 0;
            for (int it = 0; it < batch; it += 64) {
                const int idx = it + lane;
                const bool hit = (idx < batch) && (action[idx] == a);
                const unsigned long long mk = __ballot(hit);
                const int rp = base + __popcll(mk & ((1ull << lane) - 1ull)) - wlo;
                if (hit && rp >= 0 && rp < 64) slist[rp] = (ushort)idx;
                base += __popcll(mk);
            }
        }
        __syncthreads();
    }
}

extern "C" void kernel_launch(void* const* d_in, const int* in_sizes, int n_in,
                              void* d_out, int out_size, void* d_ws, size_t ws_size,
                              hipStream_t stream) {
    const float* v      = (const float*)d_in[0];
    const int*   action = (const int*)d_in[1];
    const float* W      = (const float*)d_in[2];
    float* out = (float*)d_out;
    const int batch = in_sizes[1];
    if (batch <= 0) return;

    const int nblocks = (VEC / NTILE) * NR_ACTIONS;   // 2048 (%8==0 for swizzle)
    const size_t need = (size_t)batch * VEC * sizeof(ushort);

    if (ws_size >= need && ((size_t)batch * VEC) % 8 == 0) {
        ushort* vbf = (ushort*)d_ws;
        const int n8 = (int)((size_t)batch * VEC / 8);
        cvt_v_kernel<<<(n8 + 255) / 256, 256, 0, stream>>>(v, vbf, n8);
        grouped<true><<<nblocks, 256, 0, stream>>>(v, vbf, action, W, out, batch);
    } else {
        grouped<false><<<nblocks, 256, 0, stream>>>(v, (const ushort*)nullptr,
                                                    action, W, out, batch);
    }
}